// Round 3
// baseline (104.191 us; speedup 1.0000x reference)
//
#include <hip/hip_runtime.h>
#include <hip/hip_bf16.h>

// Single fused kernel.
// out[b, i*32+j, p*32+q] = sum_{s,t} U_st(enc_bi)[p] * V_st(enc_bj)[q]
//   U_st = W_A X_msb^t P_s C_A N1_A enc ;  V_st = W_B Q_t C_B X_msb^s N1_B enc
// Wires 0..4 -> bits 4..0 of p (wire0 = MSB), wires 5..9 -> bits 4..0 of q.
// Each block: (b, i, jc) with 4 consecutive j's. Computes the 5 enc rows via
// GEMV (W is 64 KB, L2-resident), pushes them through the circuit branches
// with shfl_xor butterflies, then writes 4 x 8 KB of outer products.

__device__ __forceinline__ float2 cmulf(float2 a, float2 b) {
    return make_float2(a.x * b.x - a.y * b.y, a.x * b.y + a.y * b.x);
}
__device__ __forceinline__ float2 caddf(float2 a, float2 b) {
    return make_float2(a.x + b.x, a.y + b.y);
}
__device__ __forceinline__ float2 shflx(float2 v, int mask) {
    return make_float2(__shfl_xor(v.x, mask, 64), __shfl_xor(v.y, mask, 64));
}

// All 32 lanes of a half-wave call this with the same (side,s,t); side is
// wave-uniform at every call site, (s,t) divergence is predication-only.
__device__ __forceinline__ float2 circuit_branch(int side, int s, int t, int p,
                                                 float e_p,
                                                 const float* __restrict__ rx0,
                                                 const float* __restrict__ ry0,
                                                 const float* __restrict__ ry1) {
    int wb = side * 5;
    float2 c = make_float2(e_p, 0.f);
    // layer 1: RY(ry0)*RX(rx0) per wire; wire (wb+l) -> bit (4-l)
#pragma unroll
    for (int l = 0; l < 5; ++l) {
        float tx = rx0[wb + l] * 0.5f, ty = ry0[wb + l] * 0.5f;
        float cx = cosf(tx), sx = sinf(tx), cy = cosf(ty), sy = sinf(ty);
        int bit = 1 << (4 - l);
        float2 pr = shflx(c, bit);
        float2 g00 = make_float2(cy * cx,  sy * sx);
        float2 g01 = make_float2(-sy * cx, -cy * sx);
        float2 g10 = make_float2(sy * cx,  -cy * sx);
        float2 g11 = make_float2(cy * cx,  -sy * sx);
        c = ((p & bit) == 0) ? caddf(cmulf(g00, c), cmulf(g01, pr))
                             : caddf(cmulf(g10, pr), cmulf(g11, c));
    }
    if (side == 0) {
        // C_A chain: C(0,1) C(1,2) C(2,3) C(3,4)
#pragma unroll
        for (int l = 0; l < 4; ++l) {
            int cb = 1 << (4 - l), tb = 1 << (3 - l);
            float2 pr = shflx(c, tb);
            if (p & cb) c = pr;
        }
        if ((p & 1) != s) c = make_float2(0.f, 0.f);   // P_s (wire 4 control)
        { float2 pr = shflx(c, 16); if (t) c = pr; }   // X_msb^t (wire 0 target)
    } else {
        { float2 pr = shflx(c, 16); if (s) c = pr; }   // X_msb^s (wire 5 target)
#pragma unroll
        for (int l = 0; l < 4; ++l) {                  // C_B chain
            int cb = 1 << (4 - l), tb = 1 << (3 - l);
            float2 pr = shflx(c, tb);
            if (p & cb) c = pr;
        }
        if ((p & 1) != t) c = make_float2(0.f, 0.f);   // Q_t (wire 9 control)
    }
    // layer 2: RY(ry1)
#pragma unroll
    for (int l = 0; l < 5; ++l) {
        float ty = ry1[wb + l] * 0.5f;
        float cy = cosf(ty), sy = sinf(ty);
        int bit = 1 << (4 - l);
        float2 pr = shflx(c, bit);
        c = ((p & bit) == 0)
              ? make_float2(cy * c.x - sy * pr.x, cy * c.y - sy * pr.y)
              : make_float2(sy * pr.x + cy * c.x, sy * pr.y + cy * c.y);
    }
    return c;
}

// grid 1024: bx -> b = bx>>8, i = (bx>>3)&31, j0 = (bx&7)*4 ; block 256
__global__ __launch_bounds__(256) void fused_kernel(const float* __restrict__ x,
                                                    const float* __restrict__ W,
                                                    const float* __restrict__ bt,
                                                    const float* __restrict__ rx0,
                                                    const float* __restrict__ ry0,
                                                    const float* __restrict__ ry1,
                                                    float* __restrict__ out,
                                                    int complex_out) {
    int bx = blockIdx.x;
    int b  = bx >> 8;
    int i  = (bx >> 3) & 31;
    int j0 = (bx & 7) * 4;
    int tid = threadIdx.x;

    __shared__ float part[5][8][32];
    __shared__ float e[5][32];
    __shared__ float2 su[128];      // side A branches of enc_i:  [br*32 + p]
    __shared__ float2 sv[4][128];   // side B branches of enc_j:  [jj][br*32 + q]

    // ---- phase 1: GEMV for 5 enc rows (v=0 -> i, v=1..4 -> j0..j0+3) ----
    {
        int col = tid & 31;          // enc output column
        int seg = tid >> 5;          // 0..7, 64-float chunk of K=512
        const float4* ws = (const float4*)(W + (size_t)col * 512 + seg * 64);
        const float4* xr[5];
        int rowi = b * 32 + i;
        xr[0] = (const float4*)(x + (size_t)rowi * 512 + seg * 64);
#pragma unroll
        for (int v = 1; v < 5; ++v) {
            int row = b * 32 + j0 + (v - 1);
            xr[v] = (const float4*)(x + (size_t)row * 512 + seg * 64);
        }
        float acc[5] = {0.f, 0.f, 0.f, 0.f, 0.f};
#pragma unroll
        for (int k = 0; k < 16; ++k) {
            float4 wv = ws[k];
#pragma unroll
            for (int v = 0; v < 5; ++v) {
                float4 xv = xr[v][k];
                acc[v] += xv.x * wv.x + xv.y * wv.y + xv.z * wv.z + xv.w * wv.w;
            }
        }
#pragma unroll
        for (int v = 0; v < 5; ++v) part[v][seg][col] = acc[v];
    }
    __syncthreads();

    // ---- phase 2: reduce + bias + L2 normalize (5 rows x 32 cols = 160 thr) ----
    if (tid < 160) {
        int v = tid >> 5, col = tid & 31;
        float sum = bt[col];
#pragma unroll
        for (int g = 0; g < 8; ++g) sum += part[v][g][col];
        float sq = sum * sum;
#pragma unroll
        for (int off = 1; off < 32; off <<= 1) sq += __shfl_xor(sq, off, 64);
        e[v][col] = sum * (1.0f / sqrtf(sq));
    }
    __syncthreads();

    // ---- phase 3: circuit branches via butterflies ----
    {
        int wavepair = tid >> 7;     // uniform per wave
        int br = (tid >> 5) & 3;     // branch (s,t), per half-wave
        int s = br >> 1, t = br & 1;
        int p = tid & 31;
        if (wavepair == 0) {
            su[br * 32 + p]    = circuit_branch(0, s, t, p, e[0][p], rx0, ry0, ry1);
        } else {
            sv[0][br * 32 + p] = circuit_branch(1, s, t, p, e[1][p], rx0, ry0, ry1);
        }
        if (wavepair == 0) {
            sv[1][br * 32 + p] = circuit_branch(1, s, t, p, e[2][p], rx0, ry0, ry1);
        } else {
            sv[2][br * 32 + p] = circuit_branch(1, s, t, p, e[3][p], rx0, ry0, ry1);
        }
        if (wavepair == 0) {
            sv[3][br * 32 + p] = circuit_branch(1, s, t, p, e[4][p], rx0, ry0, ry1);
        }
    }
    __syncthreads();

    // ---- phase 4: 4 outer products, 8 KB write each ----
    int d0 = tid << 2;               // 4 consecutive q-outputs per thread
    int pp = d0 >> 5;
    int q0 = d0 & 31;
    float2 up0 = su[pp], up1 = su[32 + pp], up2 = su[64 + pp], up3 = su[96 + pp];

#pragma unroll
    for (int jj = 0; jj < 4; ++jj) {
        const float2* svj = sv[jj];
        float2 acc[4];
#pragma unroll
        for (int ee = 0; ee < 4; ++ee) {
            int q = q0 + ee;
            float2 v0 = svj[q], v1 = svj[32 + q], v2 = svj[64 + q], v3 = svj[96 + q];
            float2 a;
            a.x = up0.x * v0.x - up0.y * v0.y + up1.x * v1.x - up1.y * v1.y
                + up2.x * v2.x - up2.y * v2.y + up3.x * v3.x - up3.y * v3.y;
            a.y = up0.x * v0.y + up0.y * v0.x + up1.x * v1.y + up1.y * v1.x
                + up2.x * v2.y + up2.y * v2.x + up3.x * v3.y + up3.y * v3.x;
            acc[ee] = a;
        }
        size_t pair = (size_t)b * 1024 + (size_t)i * 32 + (j0 + jj);
        if (complex_out) {
            float4* o = (float4*)(out + (pair * 1024 + d0) * 2);
            o[0] = make_float4(acc[0].x, acc[0].y, acc[1].x, acc[1].y);
            o[1] = make_float4(acc[2].x, acc[2].y, acc[3].x, acc[3].y);
        } else {
            float4* o = (float4*)(out + pair * 1024 + d0);
            o[0] = make_float4(acc[0].x, acc[1].x, acc[2].x, acc[3].x);
        }
    }
}

extern "C" void kernel_launch(void* const* d_in, const int* in_sizes, int n_in,
                              void* d_out, int out_size, void* d_ws, size_t ws_size,
                              hipStream_t stream) {
    const float* x   = (const float*)d_in[0];   // (4,32,512)
    const float* W   = (const float*)d_in[1];   // (32,512)
    const float* bt  = (const float*)d_in[2];   // (32,)
    const float* rx0 = (const float*)d_in[3];   // (10,)
    const float* ry0 = (const float*)d_in[4];   // (10,)
    const float* ry1 = (const float*)d_in[5];   // (10,)

    int complex_out = (out_size > 4 * 1024 * 1024) ? 1 : 0;
    fused_kernel<<<1024, 256, 0, stream>>>(x, W, bt, rx0, ry0, ry1,
                                           (float*)d_out, complex_out);
}

// Round 4
// 84.592 us; speedup vs baseline: 1.2317x; 1.2317x over previous
//
#include <hip/hip_runtime.h>
#include <hip/hip_bf16.h>

// Single fused kernel, redundancy-free inner math.
// out[b, i*32+j, p*32+q] = sum_{s,t} U_st(enc_bi)[p] * V_st(enc_bj)[q]
//   U_st = W_A X_msb^t P_s C_A N1_A enc ;  V_st = W_B Q_t C_B X_msb^s N1_B enc
// Wires 0..4 -> bits 4..0 of p (wire0 = MSB), wires 5..9 -> bits 4..0 of q.
// Block = (b, i, j0..j0+3). Phases:
//  0: 10 threads build gate-coeff LDS table (trig ONCE per block, not per thread)
//  1: coalesced GEMV for the 5 needed enc rows (W reads 128B-contiguous per 8 lanes)
//  2: bias + L2 normalize
//  3: 20 circuit-branch jobs on 8 half-wave groups (3 passes, side wave-uniform)
//  4: 4 outer products -> 32 KB contiguous store per block

__device__ __forceinline__ float2 shflx(float2 v, int mask) {
    return make_float2(__shfl_xor(v.x, mask, 64), __shfl_xor(v.y, mask, 64));
}

// grid 1024: bx -> b = bx>>8, i = (bx>>3)&31, j0 = (bx&7)*4 ; block 256
__global__ __launch_bounds__(256) void fused_kernel(const float* __restrict__ x,
                                                    const float* __restrict__ W,
                                                    const float* __restrict__ bt,
                                                    const float* __restrict__ rx0,
                                                    const float* __restrict__ ry0,
                                                    const float* __restrict__ ry1,
                                                    float* __restrict__ out,
                                                    int complex_out) {
    int bx = blockIdx.x;
    int b  = bx >> 8;
    int i  = (bx >> 3) & 31;
    int j0 = (bx & 7) * 4;
    int tid = threadIdx.x;

    __shared__ float g1[10][8];     // layer1 RY*RX gate: g00x,g00y,g01x,g01y,g10x,g10y,g11x,g11y
    __shared__ float g2[10][2];     // layer2 RY: cy, sy
    __shared__ float esum[5][32];
    __shared__ float e[5][32];
    __shared__ float2 su[128];      // side-A branches of enc_i   [br*32 + p]
    __shared__ float2 sv[4][128];   // side-B branches of enc_j   [jj][br*32 + q]

    // ---- phase 0: per-wire gate coefficients (trig once per block) ----
    if (tid < 10) {
        float sx, cx, s0, c0, s1, c1;
        sincosf(rx0[tid] * 0.5f, &sx, &cx);
        sincosf(ry0[tid] * 0.5f, &s0, &c0);
        sincosf(ry1[tid] * 0.5f, &s1, &c1);
        g1[tid][0] = c0 * cx;  g1[tid][1] = s0 * sx;    // g00 = (cy*cx,  sy*sx)
        g1[tid][2] = -s0 * cx; g1[tid][3] = -c0 * sx;   // g01 = (-sy*cx, -cy*sx)
        g1[tid][4] = s0 * cx;  g1[tid][5] = -c0 * sx;   // g10 = (sy*cx,  -cy*sx)
        g1[tid][6] = c0 * cx;  g1[tid][7] = -s0 * sx;   // g11 = (cy*cx,  -sy*sx)
        g2[tid][0] = c1;       g2[tid][1] = s1;
    }

    // ---- phase 1: GEMV, coalesced W access ----
    {
        int col = tid >> 3;          // output column 0..31
        int kk  = tid & 7;           // K-slice 0..7 (64 floats each, strided)
        const float4* wp = (const float4*)(W + (size_t)col * 512 + kk * 4);
        const float4* xp[5];
        xp[0] = (const float4*)(x + (size_t)(b * 32 + i) * 512 + kk * 4);
#pragma unroll
        for (int v = 1; v < 5; ++v)
            xp[v] = (const float4*)(x + (size_t)(b * 32 + j0 + v - 1) * 512 + kk * 4);
        float acc[5] = {0.f, 0.f, 0.f, 0.f, 0.f};
#pragma unroll
        for (int m = 0; m < 16; ++m) {
            float4 wv = wp[m * 8];   // stride 32 floats
#pragma unroll
            for (int v = 0; v < 5; ++v) {
                float4 xv = xp[v][m * 8];
                acc[v] += xv.x * wv.x + xv.y * wv.y + xv.z * wv.z + xv.w * wv.w;
            }
        }
        // reduce the 8 K-slices (lanes col*8 .. col*8+7)
#pragma unroll
        for (int v = 0; v < 5; ++v) {
            acc[v] += __shfl_xor(acc[v], 1, 64);
            acc[v] += __shfl_xor(acc[v], 2, 64);
            acc[v] += __shfl_xor(acc[v], 4, 64);
        }
        if (kk == 0) {
#pragma unroll
            for (int v = 0; v < 5; ++v) esum[v][col] = acc[v];
        }
    }
    __syncthreads();

    // ---- phase 2: bias + L2 normalize (5 rows x 32 cols) ----
    if (tid < 160) {
        int v = tid >> 5, col = tid & 31;
        float sum = esum[v][col] + bt[col];
        float sq = sum * sum;
#pragma unroll
        for (int off = 1; off < 32; off <<= 1) sq += __shfl_xor(sq, off, 64);
        e[v][col] = sum * (1.0f / sqrtf(sq));
    }
    __syncthreads();

    // ---- phase 3: 20 circuit-branch jobs over 8 half-wave groups ----
    {
        int grp = tid >> 5;          // 0..7
        int p = tid & 31;
#pragma unroll
        for (int it = 0; it < 3; ++it) {
            int job = it * 8 + grp;
            if (job < 20) {
                int v = job >> 2;            // vector 0..4 (wave-uniform each pass)
                int br = job & 3;
                int s = br >> 1, t = br & 1;
                int side = (v == 0) ? 0 : 1;
                int wb = side * 5;
                float2 c = make_float2(e[v][p], 0.f);
                // layer 1: RY(ry0)*RX(rx0) butterflies
#pragma unroll
                for (int l = 0; l < 5; ++l) {
                    int w = wb + l, bit = 1 << (4 - l);
                    float2 pr = shflx(c, bit);
                    float a0 = g1[w][0], a1 = g1[w][1], a2 = g1[w][2], a3 = g1[w][3];
                    float a4 = g1[w][4], a5 = g1[w][5], a6 = g1[w][6], a7 = g1[w][7];
                    float2 lo, hi;
                    lo.x = a0 * c.x - a1 * c.y + a2 * pr.x - a3 * pr.y;
                    lo.y = a0 * c.y + a1 * c.x + a2 * pr.y + a3 * pr.x;
                    hi.x = a4 * pr.x - a5 * pr.y + a6 * c.x - a7 * c.y;
                    hi.y = a4 * pr.y + a5 * pr.x + a6 * c.y + a7 * c.x;
                    c = ((p & bit) == 0) ? lo : hi;
                }
                if (side == 0) {
                    // C_A chain: C(0,1) C(1,2) C(2,3) C(3,4)
#pragma unroll
                    for (int l = 0; l < 4; ++l) {
                        int cb = 1 << (4 - l), tb = 1 << (3 - l);
                        float2 pr = shflx(c, tb);
                        if (p & cb) c = pr;
                    }
                    if ((p & 1) != s) c = make_float2(0.f, 0.f);   // P_s
                    { float2 pr = shflx(c, 16); if (t) c = pr; }   // X_msb^t
                } else {
                    { float2 pr = shflx(c, 16); if (s) c = pr; }   // X_msb^s
#pragma unroll
                    for (int l = 0; l < 4; ++l) {                  // C_B chain
                        int cb = 1 << (4 - l), tb = 1 << (3 - l);
                        float2 pr = shflx(c, tb);
                        if (p & cb) c = pr;
                    }
                    if ((p & 1) != t) c = make_float2(0.f, 0.f);   // Q_t
                }
                // layer 2: RY(ry1)
#pragma unroll
                for (int l = 0; l < 5; ++l) {
                    int w = wb + l, bit = 1 << (4 - l);
                    float cy = g2[w][0], sy = g2[w][1];
                    float2 pr = shflx(c, bit);
                    c = ((p & bit) == 0)
                          ? make_float2(cy * c.x - sy * pr.x, cy * c.y - sy * pr.y)
                          : make_float2(sy * pr.x + cy * c.x, sy * pr.y + cy * c.y);
                }
                if (v == 0) su[br * 32 + p] = c;
                else        sv[v - 1][br * 32 + p] = c;
            }
        }
    }
    __syncthreads();

    // ---- phase 4: 4 outer products, 32 KB contiguous store per block ----
    int d0 = tid << 2;               // 4 consecutive q-outputs per thread
    int pp = d0 >> 5;
    int q0 = d0 & 31;
    float2 up0 = su[pp], up1 = su[32 + pp], up2 = su[64 + pp], up3 = su[96 + pp];

#pragma unroll
    for (int jj = 0; jj < 4; ++jj) {
        const float2* svj = sv[jj];
        float2 acc[4];
#pragma unroll
        for (int ee = 0; ee < 4; ++ee) {
            int q = q0 + ee;
            float2 v0 = svj[q], v1 = svj[32 + q], v2 = svj[64 + q], v3 = svj[96 + q];
            float2 a;
            a.x = up0.x * v0.x - up0.y * v0.y + up1.x * v1.x - up1.y * v1.y
                + up2.x * v2.x - up2.y * v2.y + up3.x * v3.x - up3.y * v3.y;
            a.y = up0.x * v0.y + up0.y * v0.x + up1.x * v1.y + up1.y * v1.x
                + up2.x * v2.y + up2.y * v2.x + up3.x * v3.y + up3.y * v3.x;
            acc[ee] = a;
        }
        size_t pair = (size_t)b * 1024 + (size_t)i * 32 + (j0 + jj);
        if (complex_out) {
            float4* o = (float4*)(out + (pair * 1024 + d0) * 2);
            o[0] = make_float4(acc[0].x, acc[0].y, acc[1].x, acc[1].y);
            o[1] = make_float4(acc[2].x, acc[2].y, acc[3].x, acc[3].y);
        } else {
            float4* o = (float4*)(out + pair * 1024 + d0);
            o[0] = make_float4(acc[0].x, acc[1].x, acc[2].x, acc[3].x);
        }
    }
}

extern "C" void kernel_launch(void* const* d_in, const int* in_sizes, int n_in,
                              void* d_out, int out_size, void* d_ws, size_t ws_size,
                              hipStream_t stream) {
    const float* x   = (const float*)d_in[0];   // (4,32,512)
    const float* W   = (const float*)d_in[1];   // (32,512)
    const float* bt  = (const float*)d_in[2];   // (32,)
    const float* rx0 = (const float*)d_in[3];   // (10,)
    const float* ry0 = (const float*)d_in[4];   // (10,)
    const float* ry1 = (const float*)d_in[5];   // (10,)

    int complex_out = (out_size > 4 * 1024 * 1024) ? 1 : 0;
    fused_kernel<<<1024, 256, 0, stream>>>(x, W, bt, rx0, ry0, ry1,
                                           (float*)d_out, complex_out);
}

// Round 6
// 74.975 us; speedup vs baseline: 1.3897x; 1.1283x over previous
//
#include <hip/hip_runtime.h>
#include <hip/hip_bf16.h>

// Two-kernel pipeline.
// out[b, i*32+j, p*32+q] = sum_{s,t} U_st(enc_bi)[p] * V_st(enc_bj)[q]
//   U_st = W_A X_msb^t P_s C_A N1_A enc ;  V_st = W_B Q_t C_B X_msb^s N1_B enc
// Wires 0..4 -> bits 4..0 of p (wire0 = MSB), wires 5..9 -> bits 4..0 of q.
// K1: 128 blocks (one enc row each): gate-table trig + coalesced GEMV +
//     8 circuit-branch jobs (8 half-wave groups, one pass) -> U,V in ws.
// K2: 1024 blocks (b, i, j0..j0+3): coalesced U/V load -> 4 outer products
//     -> 32 KB nontemporal streaming store.

typedef float vfloat4 __attribute__((ext_vector_type(4)));   // native vec for nontemporal builtin

__device__ __forceinline__ float2 shflx(float2 v, int mask) {
    return make_float2(__shfl_xor(v.x, mask, 64), __shfl_xor(v.y, mask, 64));
}

// ---------------- K1: prep ----------------
__global__ __launch_bounds__(256) void prep_kernel(const float* __restrict__ x,
                                                   const float* __restrict__ W,
                                                   const float* __restrict__ bt,
                                                   const float* __restrict__ rx0,
                                                   const float* __restrict__ ry0,
                                                   const float* __restrict__ ry1,
                                                   float2* __restrict__ U,
                                                   float2* __restrict__ V) {
    int row = blockIdx.x;            // 0..127 = b*32 + token
    int tid = threadIdx.x;

    __shared__ float g1[10][8];      // layer1 RY*RX gate coeffs
    __shared__ float g2[10][2];      // layer2 RY: cy, sy
    __shared__ float esum[32];
    __shared__ float e[32];

    // gate coefficients: trig once per block
    if (tid < 10) {
        float sx, cx, s0, c0, s1, c1;
        sincosf(rx0[tid] * 0.5f, &sx, &cx);
        sincosf(ry0[tid] * 0.5f, &s0, &c0);
        sincosf(ry1[tid] * 0.5f, &s1, &c1);
        g1[tid][0] = c0 * cx;  g1[tid][1] = s0 * sx;    // g00
        g1[tid][2] = -s0 * cx; g1[tid][3] = -c0 * sx;   // g01
        g1[tid][4] = s0 * cx;  g1[tid][5] = -c0 * sx;   // g10
        g1[tid][6] = c0 * cx;  g1[tid][7] = -s0 * sx;   // g11
        g2[tid][0] = c1;       g2[tid][1] = s1;
    }

    // GEMV: col = tid>>3 (0..31), kk = tid&7 K-slice; W reads 128B-contig per 8 lanes
    {
        int col = tid >> 3;
        int kk  = tid & 7;
        const float4* wp = (const float4*)(W + (size_t)col * 512 + kk * 4);
        const float4* xp = (const float4*)(x + (size_t)row * 512 + kk * 4);
        float acc = 0.f;
#pragma unroll
        for (int m = 0; m < 16; ++m) {
            float4 wv = wp[m * 8];
            float4 xv = xp[m * 8];
            acc += xv.x * wv.x + xv.y * wv.y + xv.z * wv.z + xv.w * wv.w;
        }
        acc += __shfl_xor(acc, 1, 64);
        acc += __shfl_xor(acc, 2, 64);
        acc += __shfl_xor(acc, 4, 64);
        if (kk == 0) esum[col] = acc;
    }
    __syncthreads();

    if (tid < 32) {
        float sum = esum[tid] + bt[tid];
        float sq = sum * sum;
#pragma unroll
        for (int off = 1; off < 32; off <<= 1) sq += __shfl_xor(sq, off, 64);
        e[tid] = sum * (1.0f / sqrtf(sq));
    }
    __syncthreads();

    // 8 circuit jobs on 8 half-wave groups: grp = side*4 + br; side wave-uniform
    {
        int grp = tid >> 5;          // 0..7
        int side = grp >> 2;         // waves 0,1 -> side 0 ; waves 2,3 -> side 1
        int br = grp & 3;
        int s = br >> 1, t = br & 1;
        int p = tid & 31;
        int wb = side * 5;
        float2 c = make_float2(e[p], 0.f);
        // layer 1 butterflies
#pragma unroll
        for (int l = 0; l < 5; ++l) {
            int w = wb + l, bit = 1 << (4 - l);
            float2 pr = shflx(c, bit);
            float a0 = g1[w][0], a1 = g1[w][1], a2 = g1[w][2], a3 = g1[w][3];
            float a4 = g1[w][4], a5 = g1[w][5], a6 = g1[w][6], a7 = g1[w][7];
            float2 lo, hi;
            lo.x = a0 * c.x - a1 * c.y + a2 * pr.x - a3 * pr.y;
            lo.y = a0 * c.y + a1 * c.x + a2 * pr.y + a3 * pr.x;
            hi.x = a4 * pr.x - a5 * pr.y + a6 * c.x - a7 * c.y;
            hi.y = a4 * pr.y + a5 * pr.x + a6 * c.y + a7 * c.x;
            c = ((p & bit) == 0) ? lo : hi;
        }
        if (side == 0) {
#pragma unroll
            for (int l = 0; l < 4; ++l) {              // C_A chain
                int cb = 1 << (4 - l), tb = 1 << (3 - l);
                float2 pr = shflx(c, tb);
                if (p & cb) c = pr;
            }
            if ((p & 1) != s) c = make_float2(0.f, 0.f);   // P_s
            { float2 pr = shflx(c, 16); if (t) c = pr; }   // X_msb^t
        } else {
            { float2 pr = shflx(c, 16); if (s) c = pr; }   // X_msb^s
#pragma unroll
            for (int l = 0; l < 4; ++l) {              // C_B chain
                int cb = 1 << (4 - l), tb = 1 << (3 - l);
                float2 pr = shflx(c, tb);
                if (p & cb) c = pr;
            }
            if ((p & 1) != t) c = make_float2(0.f, 0.f);   // Q_t
        }
        // layer 2 RY
#pragma unroll
        for (int l = 0; l < 5; ++l) {
            int w = wb + l, bit = 1 << (4 - l);
            float cy = g2[w][0], sy = g2[w][1];
            float2 pr = shflx(c, bit);
            c = ((p & bit) == 0)
                  ? make_float2(cy * c.x - sy * pr.x, cy * c.y - sy * pr.y)
                  : make_float2(sy * pr.x + cy * c.x, sy * pr.y + cy * c.y);
        }
        float2* dst = (side == 0) ? U : V;
        dst[(size_t)row * 128 + br * 32 + p] = c;
    }
}

// ---------------- K2: outer products ----------------
// grid 1024: b = bx>>8, i = (bx>>3)&31, j0 = (bx&7)*4 ; block 256
__global__ __launch_bounds__(256) void outer_kernel(const float2* __restrict__ U,
                                                    const float2* __restrict__ V,
                                                    float* __restrict__ out,
                                                    int complex_out) {
    int bx = blockIdx.x;
    int b  = bx >> 8;
    int i  = (bx >> 3) & 31;
    int j0 = (bx & 7) * 4;
    int tid = threadIdx.x;

    __shared__ float2 su[128];       // U branches of enc_i
    __shared__ float2 sv[4][128];    // V branches of enc_{j0..j0+3} (contiguous rows)

    if (tid < 64)
        ((float4*)su)[tid] = ((const float4*)(U + (size_t)(b * 32 + i) * 128))[tid];
    ((float4*)sv)[tid] = ((const float4*)(V + (size_t)(b * 32 + j0) * 128))[tid];
    __syncthreads();

    int d0 = tid << 2;               // 4 consecutive q-outputs per thread
    int pp = d0 >> 5;
    int q0 = d0 & 31;
    float2 up0 = su[pp], up1 = su[32 + pp], up2 = su[64 + pp], up3 = su[96 + pp];

#pragma unroll
    for (int jj = 0; jj < 4; ++jj) {
        const float2* svj = sv[jj];
        float2 acc[4];
#pragma unroll
        for (int ee = 0; ee < 4; ++ee) {
            int q = q0 + ee;
            float2 v0 = svj[q], v1 = svj[32 + q], v2 = svj[64 + q], v3 = svj[96 + q];
            float2 a;
            a.x = up0.x * v0.x - up0.y * v0.y + up1.x * v1.x - up1.y * v1.y
                + up2.x * v2.x - up2.y * v2.y + up3.x * v3.x - up3.y * v3.y;
            a.y = up0.x * v0.y + up0.y * v0.x + up1.x * v1.y + up1.y * v1.x
                + up2.x * v2.y + up2.y * v2.x + up3.x * v3.y + up3.y * v3.x;
            acc[ee] = a;
        }
        size_t pair = (size_t)b * 1024 + (size_t)i * 32 + (j0 + jj);
        if (complex_out) {
            vfloat4* o = (vfloat4*)(out + (pair * 1024 + d0) * 2);
            vfloat4 w0 = {acc[0].x, acc[0].y, acc[1].x, acc[1].y};
            vfloat4 w1 = {acc[2].x, acc[2].y, acc[3].x, acc[3].y};
            __builtin_nontemporal_store(w0, o);
            __builtin_nontemporal_store(w1, o + 1);
        } else {
            vfloat4* o = (vfloat4*)(out + pair * 1024 + d0);
            vfloat4 w0 = {acc[0].x, acc[1].x, acc[2].x, acc[3].x};
            __builtin_nontemporal_store(w0, o);
        }
    }
}

extern "C" void kernel_launch(void* const* d_in, const int* in_sizes, int n_in,
                              void* d_out, int out_size, void* d_ws, size_t ws_size,
                              hipStream_t stream) {
    const float* x   = (const float*)d_in[0];   // (4,32,512)
    const float* W   = (const float*)d_in[1];   // (32,512)
    const float* bt  = (const float*)d_in[2];   // (32,)
    const float* rx0 = (const float*)d_in[3];   // (10,)
    const float* ry0 = (const float*)d_in[4];   // (10,)
    const float* ry1 = (const float*)d_in[5];   // (10,)

    // ws layout (float2): U 128*128 | V 128*128  (256 KB total)
    float2* U = (float2*)d_ws;
    float2* V = U + 16384;

    prep_kernel<<<128, 256, 0, stream>>>(x, W, bt, rx0, ry0, ry1, U, V);

    int complex_out = (out_size > 4 * 1024 * 1024) ? 1 : 0;
    outer_kernel<<<1024, 256, 0, stream>>>(U, V, (float*)d_out, complex_out);
}